// Round 1
// baseline (5132.354 us; speedup 1.0000x reference)
//
#include <hip/hip_runtime.h>
#include <math.h>

namespace {

constexpr int T = 5, N = 2048, K = 20, E = 512;
constexpr int H = 64, U = 8;
constexpr int CAP = 512;           // max neighbors kept (measured mean ~103, max ~145)
constexpr float SLOPE = 0.01f;

__device__ inline float sigm(float x) { return 1.0f / (1.0f + expf(-x)); }

// ---------------- Kernel 1: GRU over p, q = sum_t h ----------------
// wave per sequence, lane owns hidden unit; h shared via LDS.
__global__ __launch_bounds__(256) void k_gru_p(
    const float* __restrict__ p, const float* __restrict__ Wih,
    const float* __restrict__ Whh, const float* __restrict__ bih,
    const float* __restrict__ bhh, float* __restrict__ q)
{
  __shared__ float hs[4][H];
  const int w = threadIdx.x >> 6, lane = threadIdx.x & 63;
  const int n = blockIdx.x * 4 + w;
  hs[w][lane] = 0.f;
  float h = 0.f, qs = 0.f;
  __syncthreads();
  for (int t = 0; t < T; ++t) {
    const float x0 = p[n * (T * 3) + t * 3 + 0];
    const float x1 = p[n * (T * 3) + t * 3 + 1];
    const float x2 = p[n * (T * 3) + t * 3 + 2];
    float gr = bih[lane]     + Wih[lane * 3] * x0       + Wih[lane * 3 + 1] * x1       + Wih[lane * 3 + 2] * x2;
    float gz = bih[64 + lane]  + Wih[(64 + lane) * 3] * x0  + Wih[(64 + lane) * 3 + 1] * x1  + Wih[(64 + lane) * 3 + 2] * x2;
    float gn = bih[128 + lane] + Wih[(128 + lane) * 3] * x0 + Wih[(128 + lane) * 3 + 1] * x1 + Wih[(128 + lane) * 3 + 2] * x2;
    float hr = bhh[lane], hz = bhh[64 + lane], hn = bhh[128 + lane];
    #pragma unroll 8
    for (int k2 = 0; k2 < H; ++k2) {
      const float hk = hs[w][k2];
      hr += Whh[lane * H + k2] * hk;
      hz += Whh[(64 + lane) * H + k2] * hk;
      hn += Whh[(128 + lane) * H + k2] * hk;
    }
    const float r = sigm(gr + hr), z = sigm(gz + hz);
    const float nn = tanhf(gn + r * hn);
    h = (1.f - z) * nn + z * h;
    qs += h;
    __syncthreads();
    hs[w][lane] = h;
    __syncthreads();
  }
  q[n * H + lane] = qs;
}

// ---------------- Kernel 2: GRU over m (the heavy one), r = sum_k h ----------------
// 192 threads, 8 sequences per block. Phase A: thread t computes gi row t for all
// 8 sequences (Wih element read once per block-step; x broadcast from LDS float4).
// Phase B: (seq,unit) pairs, unit fixed per thread so Whh rows are reused.
__global__ __launch_bounds__(192) void k_gru_m(
    const float* __restrict__ m, const float* __restrict__ Wih,
    const float* __restrict__ Whh, const float* __restrict__ bih,
    const float* __restrict__ bhh, float* __restrict__ rout)
{
  __shared__ float4 xs[8][E / 4];   // 16 KB
  __shared__ float gis[8][192];     // 6 KB
  __shared__ float hs[8][H];        // 2 KB
  const int tid = threadIdx.x;
  const int s0 = blockIdx.x * 8;
  for (int idx = tid; idx < 8 * H; idx += 192) hs[idx >> 6][idx & 63] = 0.f;
  const int row = tid;              // 0..191 : gi row (gate*64 + unit)
  const float brow = bih[row];
  const int iu = tid & 63;          // hidden unit owned in phase B
  const int w = tid >> 6;
  float rsum[3] = {0.f, 0.f, 0.f};
  const float4* __restrict__ wrow = reinterpret_cast<const float4*>(Wih) + row * (E / 4);
  __syncthreads();

  for (int k = 0; k < K; ++k) {
    // stage x for 8 sequences
    for (int idx = tid; idx < 8 * (E / 4); idx += 192) {
      const int sl = idx >> 7, e4 = idx & 127;
      xs[sl][e4] = reinterpret_cast<const float4*>(m)[(long)((s0 + sl) * K + k) * (E / 4) + e4];
    }
    __syncthreads();

    // phase A: gi[sl][row]
    float acc[8];
    #pragma unroll
    for (int sl = 0; sl < 8; ++sl) acc[sl] = brow;
    for (int e4 = 0; e4 < E / 4; ++e4) {
      const float4 wv = wrow[e4];
      #pragma unroll
      for (int sl = 0; sl < 8; ++sl) {
        const float4 xv = xs[sl][e4];
        acc[sl] += wv.x * xv.x + wv.y * xv.y + wv.z * xv.z + wv.w * xv.w;
      }
    }
    #pragma unroll
    for (int sl = 0; sl < 8; ++sl) gis[sl][row] = acc[sl];
    __syncthreads();

    // phase B: gh + gate update. pairs: sl = w + 3*ii (sl<8), unit iu.
    float aR[3], aZ[3], aN[3], hnew[3];
    #pragma unroll
    for (int ii = 0; ii < 3; ++ii) { aR[ii] = bhh[iu]; aZ[ii] = bhh[64 + iu]; aN[ii] = bhh[128 + iu]; }
    #pragma unroll 4
    for (int k2 = 0; k2 < H; ++k2) {
      const float wr = Whh[iu * H + k2];
      const float wz = Whh[(64 + iu) * H + k2];
      const float wn = Whh[(128 + iu) * H + k2];
      #pragma unroll
      for (int ii = 0; ii < 3; ++ii) {
        const int sl = w + 3 * ii;
        if (sl < 8) {
          const float hk = hs[sl][k2];
          aR[ii] += wr * hk; aZ[ii] += wz * hk; aN[ii] += wn * hk;
        }
      }
    }
    #pragma unroll
    for (int ii = 0; ii < 3; ++ii) {
      const int sl = w + 3 * ii;
      if (sl < 8) {
        const float rr = sigm(gis[sl][iu] + aR[ii]);
        const float zz = sigm(gis[sl][64 + iu] + aZ[ii]);
        const float nn = tanhf(gis[sl][128 + iu] + rr * aN[ii]);
        hnew[ii] = (1.f - zz) * nn + zz * hs[sl][iu];
        rsum[ii] += hnew[ii];
      }
    }
    __syncthreads();
    #pragma unroll
    for (int ii = 0; ii < 3; ++ii) {
      const int sl = w + 3 * ii;
      if (sl < 8) hs[sl][iu] = hnew[ii];
    }
    __syncthreads();
  }

  // write r as [N, T, H]
  #pragma unroll
  for (int ii = 0; ii < 3; ++ii) {
    const int sl = w + 3 * ii;
    if (sl < 8) {
      const int s = s0 + sl;
      const int tt = s / N, n = s % N;
      rout[(n * T + tt) * H + iu] = rsum[ii];
    }
  }
}

// ---------------- Kernel 3: GRU over r, c = sum_t h ----------------
__global__ __launch_bounds__(256) void k_gru_s(
    const float* __restrict__ rin, const float* __restrict__ Wih,
    const float* __restrict__ Whh, const float* __restrict__ bih,
    const float* __restrict__ bhh, float* __restrict__ c)
{
  __shared__ float hs[4][H];
  __shared__ float xsh[4][H];
  const int w = threadIdx.x >> 6, lane = threadIdx.x & 63;
  const int n = blockIdx.x * 4 + w;
  hs[w][lane] = 0.f;
  float h = 0.f, cs = 0.f;
  __syncthreads();
  for (int t = 0; t < T; ++t) {
    xsh[w][lane] = rin[(n * T + t) * H + lane];
    __syncthreads();
    float gr = bih[lane], gz = bih[64 + lane], gn = bih[128 + lane];
    float hr = bhh[lane], hz = bhh[64 + lane], hn = bhh[128 + lane];
    #pragma unroll 8
    for (int k2 = 0; k2 < H; ++k2) {
      const float xk = xsh[w][k2];
      const float hk = hs[w][k2];
      gr += Wih[lane * H + k2] * xk;  gz += Wih[(64 + lane) * H + k2] * xk;  gn += Wih[(128 + lane) * H + k2] * xk;
      hr += Whh[lane * H + k2] * hk;  hz += Whh[(64 + lane) * H + k2] * hk;  hn += Whh[(128 + lane) * H + k2] * hk;
    }
    const float r = sigm(gr + hr), z = sigm(gz + hz);
    const float nn = tanhf(gn + r * hn);
    h = (1.f - z) * nn + z * h;
    cs += h;
    __syncthreads();
    hs[w][lane] = h;
    __syncthreads();
  }
  c[n * H + lane] = cs;
}

// ---------------- Kernel 4: bilinear blend + relu ----------------
__global__ __launch_bounds__(256) void k_blend(
    const float* __restrict__ q, const float* __restrict__ c,
    const float* __restrict__ W, const float* __restrict__ b,
    float* __restrict__ xout)
{
  __shared__ alignas(16) float qs[4][H];
  __shared__ alignas(16) float cs[4][H];
  const int nl = threadIdx.x >> 6, o = threadIdx.x & 63;
  const int n = blockIdx.x * 4 + nl;
  qs[nl][o] = q[n * H + o];
  cs[nl][o] = c[n * H + o];
  __syncthreads();
  float acc = b[o];
  const float4* __restrict__ W4 = reinterpret_cast<const float4*>(W) + o * (H * H / 4);
  const float4* c4 = reinterpret_cast<const float4*>(&cs[nl][0]);
  for (int i = 0; i < H; ++i) {
    float part = 0.f;
    #pragma unroll 4
    for (int j4 = 0; j4 < H / 4; ++j4) {
      const float4 wv = W4[i * (H / 4) + j4];
      const float4 cv = c4[j4];
      part += wv.x * cv.x + wv.y * cv.y + wv.z * cv.z + wv.w * cv.w;
    }
    acc += qs[nl][i] * part;
  }
  xout[n * H + o] = fmaxf(acc, 0.f);
}

// ---------------- Kernel 5: adjacency compaction ----------------
__global__ __launch_bounds__(256) void k_compact(
    const float* __restrict__ adj, int* __restrict__ nbr, int* __restrict__ deg)
{
  const int w = threadIdx.x >> 6, lane = threadIdx.x & 63;
  const int i = blockIdx.x * 4 + w;
  int base = 0;
  for (int j0 = 0; j0 < N; j0 += 64) {
    const float v = adj[(long)i * N + j0 + lane];
    const unsigned long long mask = __ballot(v > 0.f);
    const int pre = __popcll(mask & ((1ull << lane) - 1ull));
    if (v > 0.f && base + pre < CAP) nbr[i * CAP + base + pre] = j0 + lane;
    base += __popcll(mask);
  }
  if (lane == 0) deg[i] = base < CAP ? base : CAP;
}

// ---------------- Kernel 6: GAT precompute Wh, s1, s2 ----------------
__global__ __launch_bounds__(256) void k_gat_pre(
    const float* __restrict__ x, const float* __restrict__ W,
    const float* __restrict__ a, const int F,
    float* __restrict__ Wh, float* __restrict__ s1, float* __restrict__ s2)
{
  const int nl = threadIdx.x >> 6, o = threadIdx.x & 63;
  const int n = blockIdx.x * 4 + nl;
  const int u = blockIdx.y;
  const float* __restrict__ Wu = W + (long)u * F * 64;
  const float* __restrict__ xn = x + (long)n * F;
  float acc = 0.f;
  #pragma unroll 8
  for (int f = 0; f < F; ++f) acc += xn[f] * Wu[f * 64 + o];
  Wh[((long)u * N + n) * 64 + o] = acc;
  float p1 = acc * a[u * 128 + o];
  float p2 = acc * a[u * 128 + 64 + o];
  #pragma unroll
  for (int d = 32; d > 0; d >>= 1) { p1 += __shfl_xor(p1, d, 64); p2 += __shfl_xor(p2, d, 64); }
  if (o == 0) { s1[u * N + n] = p1; s2[u * N + n] = p2; }
}

// ---------------- Kernel 7: GAT attention (sparse, compacted) ----------------
// mode 0: elu epilogue (layer 1) ; mode 1: sigmoid epilogue (layer 2)
__global__ __launch_bounds__(256) void k_gat_attn(
    const float* __restrict__ Wh, const float* __restrict__ s1,
    const float* __restrict__ s2, const int* __restrict__ nbr,
    const int* __restrict__ deg, const int mode, float* __restrict__ out)
{
  __shared__ float ew[4][CAP];
  __shared__ int nb[4][CAP];
  const int w = threadIdx.x >> 6, lane = threadIdx.x & 63;
  const int row = blockIdx.x * 4 + w;
  const int u = row >> 11;          // / N
  const int i = row & (N - 1);
  const int d = deg[i];
  const float su = s1[u * N + i];
  float mx = -1e30f;
  for (int t = lane; t < d; t += 64) {
    const int j = nbr[i * CAP + t];
    float e = su + s2[u * N + j];
    e = e > 0.f ? e : SLOPE * e;
    ew[w][t] = e; nb[w][t] = j;
    mx = fmaxf(mx, e);
  }
  #pragma unroll
  for (int dd = 32; dd > 0; dd >>= 1) mx = fmaxf(mx, __shfl_xor(mx, dd, 64));
  float sm = 0.f;
  for (int t = lane; t < d; t += 64) {
    const float ex = expf(ew[w][t] - mx);
    ew[w][t] = ex;
    sm += ex;
  }
  #pragma unroll
  for (int dd = 32; dd > 0; dd >>= 1) sm += __shfl_xor(sm, dd, 64);
  __syncthreads();
  const float inv = 1.f / sm;
  float acc = 0.f;
  for (int t = 0; t < d; ++t) {
    const float att = ew[w][t];
    const int j = nb[w][t];
    acc += att * Wh[((long)u * N + j) * 64 + lane];
  }
  acc *= inv;
  float val;
  if (mode == 0) val = acc > 0.f ? acc : (expf(acc) - 1.f);   // elu, alpha=1
  else           val = 1.f / (1.f + expf(-acc));              // sigmoid
  out[(long)i * (U * 64) + u * 64 + lane] = val;
}

// ---------------- Kernel 8: final projection + sigmoid ----------------
__global__ __launch_bounds__(256) void k_final(
    const float* __restrict__ nz, const float* __restrict__ fw,
    const float* __restrict__ fb, float* __restrict__ out)
{
  const int w = threadIdx.x >> 6, lane = threadIdx.x & 63;
  const int n = blockIdx.x * 4 + w;
  float p = 0.f;
  #pragma unroll
  for (int f = lane; f < 512; f += 64) p += nz[(long)n * 512 + f] * fw[f];
  #pragma unroll
  for (int d = 32; d > 0; d >>= 1) p += __shfl_xor(p, d, 64);
  if (lane == 0) out[n] = 1.f / (1.f + expf(-(p + fb[0])));
}

}  // namespace

extern "C" void kernel_launch(void* const* d_in, const int* in_sizes, int n_in,
                              void* d_out, int out_size, void* d_ws, size_t ws_size,
                              hipStream_t stream)
{
  const float* p     = (const float*)d_in[0];
  const float* m     = (const float*)d_in[1];
  const float* adj   = (const float*)d_in[2];
  const float* Wih_p = (const float*)d_in[3];
  const float* Whh_p = (const float*)d_in[4];
  const float* bih_p = (const float*)d_in[5];
  const float* bhh_p = (const float*)d_in[6];
  const float* Wih_m = (const float*)d_in[7];
  const float* Whh_m = (const float*)d_in[8];
  const float* bih_m = (const float*)d_in[9];
  const float* bhh_m = (const float*)d_in[10];
  const float* Wih_s = (const float*)d_in[11];
  const float* Whh_s = (const float*)d_in[12];
  const float* bih_s = (const float*)d_in[13];
  const float* bhh_s = (const float*)d_in[14];
  // d_in[15..23]: lin-attn weights — mathematically unused (softmax over size-1 axis == 1)
  const float* blend_W = (const float*)d_in[24];
  const float* blend_b = (const float*)d_in[25];
  const float* g1W = (const float*)d_in[26];
  const float* g1a = (const float*)d_in[27];
  const float* g2W = (const float*)d_in[28];
  const float* g2a = (const float*)d_in[29];
  const float* finW = (const float*)d_in[30];
  const float* finb = (const float*)d_in[31];

  float* ws = (float*)d_ws;
  float* q   = ws;                  // N*H
  float* rr  = q + N * H;           // N*T*H
  float* c   = rr + N * T * H;      // N*H
  float* xb  = c + N * H;           // N*H
  float* Wh1 = xb + N * H;          // U*N*64
  float* s1a = Wh1 + U * N * 64;    // U*N
  float* s2a = s1a + U * N;         // U*N
  float* z   = s2a + U * N;         // N*512
  float* Wh2 = z + (long)N * 512;   // U*N*64
  float* s1b = Wh2 + U * N * 64;    // U*N
  float* s2b = s1b + U * N;         // U*N
  float* nz  = s2b + U * N;         // N*512
  int* nbr   = (int*)(nz + (long)N * 512);  // N*CAP ints
  int* deg   = nbr + (long)N * CAP;         // N ints

  k_gru_p<<<N / 4, 256, 0, stream>>>(p, Wih_p, Whh_p, bih_p, bhh_p, q);
  k_gru_m<<<(T * N) / 8, 192, 0, stream>>>(m, Wih_m, Whh_m, bih_m, bhh_m, rr);
  k_gru_s<<<N / 4, 256, 0, stream>>>(rr, Wih_s, Whh_s, bih_s, bhh_s, c);
  k_blend<<<N / 4, 256, 0, stream>>>(q, c, blend_W, blend_b, xb);
  k_compact<<<N / 4, 256, 0, stream>>>(adj, nbr, deg);
  k_gat_pre<<<dim3(N / 4, U), 256, 0, stream>>>(xb, g1W, g1a, 64, Wh1, s1a, s2a);
  k_gat_attn<<<(U * N) / 4, 256, 0, stream>>>(Wh1, s1a, s2a, nbr, deg, 0, z);
  k_gat_pre<<<dim3(N / 4, U), 256, 0, stream>>>(z, g2W, g2a, 512, Wh2, s1b, s2b);
  k_gat_attn<<<(U * N) / 4, 256, 0, stream>>>(Wh2, s1b, s2b, nbr, deg, 1, nz);
  k_final<<<N / 4, 256, 0, stream>>>(nz, finW, finb, (float*)d_out);
}

// Round 2
// 1412.200 us; speedup vs baseline: 3.6343x; 3.6343x over previous
//
#include <hip/hip_runtime.h>
#include <math.h>

namespace {

constexpr int T = 5, N = 2048, K = 20, E = 512;
constexpr int H = 64, U = 8;
constexpr int CAP = 512;           // max neighbors kept (measured mean ~103)
constexpr float SLOPE = 0.01f;

typedef __attribute__((ext_vector_type(8))) short short8;
typedef __attribute__((ext_vector_type(4))) float f32x4;

__device__ inline float sigm(float x) { return 1.0f / (1.0f + expf(-x)); }

// split fp32 -> bf16 hi + bf16 lo (truncation; x ~= hi+lo with rel err <= 2^-16)
__device__ inline void bsplit(float x, short& hi, short& lo) {
  unsigned u = __float_as_uint(x);
  hi = (short)(u >> 16);
  float r = x - __uint_as_float(u & 0xFFFF0000u);
  lo = (short)(__float_as_uint(r) >> 16);
}

// ---------------- prep: Wih_m -> bf16 hi/lo, Whh_m -> transposed fp32 ----------------
__global__ __launch_bounds__(256) void k_prep(
    const float* __restrict__ Wih, const float* __restrict__ Whh,
    short* __restrict__ WihH, short* __restrict__ WihL, float* __restrict__ WhhT)
{
  for (int idx = threadIdx.x + blockIdx.x * 256; idx < 192 * E; idx += 256 * 64) {
    short hi, lo; bsplit(Wih[idx], hi, lo);
    WihH[idx] = hi; WihL[idx] = lo;
  }
  for (int idx = threadIdx.x + blockIdx.x * 256; idx < 64 * 192; idx += 256 * 64) {
    const int k2 = idx / 192, row = idx % 192;
    WhhT[idx] = Whh[row * 64 + k2];
  }
}

// ---------------- gi GEMM: [rows,512] x [512,192] via bf16 MFMA, split-precision ----
// wave handles 16 rows x all 192 cols. A converted inline from fp32 m.
__global__ __launch_bounds__(256) void k_gemm(
    const float* __restrict__ m, const short* __restrict__ WihH,
    const short* __restrict__ WihL, const float* __restrict__ bih,
    float* __restrict__ gi, const int row0)
{
  const int w = threadIdx.x >> 6, l = threadIdx.x & 63;
  const int mloc = (blockIdx.x * 4 + w) * 16;       // local row base (gi index)
  const int lr = l & 15, lk = (l >> 4) * 8;
  f32x4 acc[12];
  #pragma unroll
  for (int nt = 0; nt < 12; ++nt) acc[nt] = (f32x4){0.f, 0.f, 0.f, 0.f};

  const float* __restrict__ arow = m + (long)(row0 + mloc + lr) * E + lk;

  for (int k0 = 0; k0 < E; k0 += 32) {
    const float4 a0 = *reinterpret_cast<const float4*>(arow + k0);
    const float4 a1 = *reinterpret_cast<const float4*>(arow + k0 + 4);
    short8 ah, al;
    {
      short h0,l0,h1,l1,h2,l2,h3,l3,h4,l4,h5,l5,h6,l6,h7,l7;
      bsplit(a0.x,h0,l0); bsplit(a0.y,h1,l1); bsplit(a0.z,h2,l2); bsplit(a0.w,h3,l3);
      bsplit(a1.x,h4,l4); bsplit(a1.y,h5,l5); bsplit(a1.z,h6,l6); bsplit(a1.w,h7,l7);
      ah = (short8){h0,h1,h2,h3,h4,h5,h6,h7};
      al = (short8){l0,l1,l2,l3,l4,l5,l6,l7};
    }
    const int boff = k0 + lk;
    #pragma unroll
    for (int nt = 0; nt < 12; ++nt) {
      const short8 bh = *reinterpret_cast<const short8*>(WihH + (nt * 16 + lr) * E + boff);
      const short8 bl = *reinterpret_cast<const short8*>(WihL + (nt * 16 + lr) * E + boff);
      acc[nt] = __builtin_amdgcn_mfma_f32_16x16x32_bf16(ah, bh, acc[nt], 0, 0, 0);
      acc[nt] = __builtin_amdgcn_mfma_f32_16x16x32_bf16(al, bh, acc[nt], 0, 0, 0);
      acc[nt] = __builtin_amdgcn_mfma_f32_16x16x32_bf16(ah, bl, acc[nt], 0, 0, 0);
    }
  }
  // C/D layout: col = lane&15, row = (lane>>4)*4 + reg  [verified m89/m91]
  #pragma unroll
  for (int nt = 0; nt < 12; ++nt) {
    const int col = nt * 16 + lr;
    const float bb = bih[col];
    #pragma unroll
    for (int i = 0; i < 4; ++i) {
      const int r = mloc + (l >> 4) * 4 + i;
      gi[(long)r * 192 + col] = acc[nt][i] + bb;
    }
  }
}

// ---------------- recurrence over K=20 using precomputed gi ----------------
// block: 256 thr = 4 waves, 16 sequences; WhhT staged in LDS (lane-coalesced).
__global__ __launch_bounds__(256) void k_recur(
    const float* __restrict__ gi, const float* __restrict__ WhhT,
    const float* __restrict__ bhh, float* __restrict__ rout, const int seq0)
{
  __shared__ float wsh[64][192];   // 48 KB
  __shared__ float hs[16][64];     // 4 KB
  const int tid = threadIdx.x;
  for (int idx = tid; idx < 64 * 192; idx += 256) wsh[idx / 192][idx % 192] = WhhT[idx];
  for (int idx = tid; idx < 16 * 64; idx += 256) hs[idx >> 6][idx & 63] = 0.f;
  __syncthreads();

  const int w = tid >> 6, l = tid & 63;
  const int sl0 = w * 4;                       // local seqs sl0..sl0+3
  const int lseq0 = blockIdx.x * 16 + sl0;     // chunk-local
  const float bR = bhh[l], bZ = bhh[64 + l], bN = bhh[128 + l];
  float rsum[4] = {0.f, 0.f, 0.f, 0.f};

  for (int k = 0; k < K; ++k) {
    float aR[4], aZ[4], aN[4], gR[4], gZ[4], gN[4];
    #pragma unroll
    for (int ii = 0; ii < 4; ++ii) {
      const long row = ((long)(lseq0 + ii) * K + k) * 192;
      gR[ii] = gi[row + l]; gZ[ii] = gi[row + 64 + l]; gN[ii] = gi[row + 128 + l];
      aR[ii] = bR; aZ[ii] = bZ; aN[ii] = bN;
    }
    #pragma unroll 4
    for (int k2 = 0; k2 < H; ++k2) {
      const float wr = wsh[k2][l], wz = wsh[k2][64 + l], wn = wsh[k2][128 + l];
      #pragma unroll
      for (int ii = 0; ii < 4; ++ii) {
        const float hk = hs[sl0 + ii][k2];
        aR[ii] += wr * hk; aZ[ii] += wz * hk; aN[ii] += wn * hk;
      }
    }
    #pragma unroll
    for (int ii = 0; ii < 4; ++ii) {
      const float r = sigm(gR[ii] + aR[ii]);
      const float z = sigm(gZ[ii] + aZ[ii]);
      const float nn = tanhf(gN[ii] + r * aN[ii]);
      const float h = (1.f - z) * nn + z * hs[sl0 + ii][l];
      rsum[ii] += h;
      hs[sl0 + ii][l] = h;     // wave-private rows; in-order within wave
    }
  }
  #pragma unroll
  for (int ii = 0; ii < 4; ++ii) {
    const int gseq = seq0 + lseq0 + ii;
    const int tt = gseq / N, n = gseq % N;
    rout[(n * T + tt) * H + l] = rsum[ii];
  }
}

// ---------------- GRU over p, q = sum_t h ----------------
__global__ __launch_bounds__(256) void k_gru_p(
    const float* __restrict__ p, const float* __restrict__ Wih,
    const float* __restrict__ Whh, const float* __restrict__ bih,
    const float* __restrict__ bhh, float* __restrict__ q)
{
  __shared__ float hs[4][H];
  const int w = threadIdx.x >> 6, lane = threadIdx.x & 63;
  const int n = blockIdx.x * 4 + w;
  hs[w][lane] = 0.f;
  float h = 0.f, qs = 0.f;
  __syncthreads();
  for (int t = 0; t < T; ++t) {
    const float x0 = p[n * (T * 3) + t * 3 + 0];
    const float x1 = p[n * (T * 3) + t * 3 + 1];
    const float x2 = p[n * (T * 3) + t * 3 + 2];
    float gr = bih[lane]     + Wih[lane * 3] * x0       + Wih[lane * 3 + 1] * x1       + Wih[lane * 3 + 2] * x2;
    float gz = bih[64 + lane]  + Wih[(64 + lane) * 3] * x0  + Wih[(64 + lane) * 3 + 1] * x1  + Wih[(64 + lane) * 3 + 2] * x2;
    float gn = bih[128 + lane] + Wih[(128 + lane) * 3] * x0 + Wih[(128 + lane) * 3 + 1] * x1 + Wih[(128 + lane) * 3 + 2] * x2;
    float hr = bhh[lane], hz = bhh[64 + lane], hn = bhh[128 + lane];
    #pragma unroll 8
    for (int k2 = 0; k2 < H; ++k2) {
      const float hk = hs[w][k2];
      hr += Whh[lane * H + k2] * hk;
      hz += Whh[(64 + lane) * H + k2] * hk;
      hn += Whh[(128 + lane) * H + k2] * hk;
    }
    const float r = sigm(gr + hr), z = sigm(gz + hz);
    const float nn = tanhf(gn + r * hn);
    h = (1.f - z) * nn + z * h;
    qs += h;
    __syncthreads();
    hs[w][lane] = h;
    __syncthreads();
  }
  q[n * H + lane] = qs;
}

// ---------------- GRU over r, c = sum_t h ----------------
__global__ __launch_bounds__(256) void k_gru_s(
    const float* __restrict__ rin, const float* __restrict__ Wih,
    const float* __restrict__ Whh, const float* __restrict__ bih,
    const float* __restrict__ bhh, float* __restrict__ c)
{
  __shared__ float hs[4][H];
  __shared__ float xsh[4][H];
  const int w = threadIdx.x >> 6, lane = threadIdx.x & 63;
  const int n = blockIdx.x * 4 + w;
  hs[w][lane] = 0.f;
  float h = 0.f, cs = 0.f;
  __syncthreads();
  for (int t = 0; t < T; ++t) {
    xsh[w][lane] = rin[(n * T + t) * H + lane];
    __syncthreads();
    float gr = bih[lane], gz = bih[64 + lane], gn = bih[128 + lane];
    float hr = bhh[lane], hz = bhh[64 + lane], hn = bhh[128 + lane];
    #pragma unroll 8
    for (int k2 = 0; k2 < H; ++k2) {
      const float xk = xsh[w][k2];
      const float hk = hs[w][k2];
      gr += Wih[lane * H + k2] * xk;  gz += Wih[(64 + lane) * H + k2] * xk;  gn += Wih[(128 + lane) * H + k2] * xk;
      hr += Whh[lane * H + k2] * hk;  hz += Whh[(64 + lane) * H + k2] * hk;  hn += Whh[(128 + lane) * H + k2] * hk;
    }
    const float r = sigm(gr + hr), z = sigm(gz + hz);
    const float nn = tanhf(gn + r * hn);
    h = (1.f - z) * nn + z * h;
    cs += h;
    __syncthreads();
    hs[w][lane] = h;
    __syncthreads();
  }
  c[n * H + lane] = cs;
}

// ---------------- bilinear blend + relu ----------------
__global__ __launch_bounds__(256) void k_blend(
    const float* __restrict__ q, const float* __restrict__ c,
    const float* __restrict__ W, const float* __restrict__ b,
    float* __restrict__ xout)
{
  __shared__ alignas(16) float qs[4][H];
  __shared__ alignas(16) float cs[4][H];
  const int nl = threadIdx.x >> 6, o = threadIdx.x & 63;
  const int n = blockIdx.x * 4 + nl;
  qs[nl][o] = q[n * H + o];
  cs[nl][o] = c[n * H + o];
  __syncthreads();
  float acc = b[o];
  const float4* __restrict__ W4 = reinterpret_cast<const float4*>(W) + o * (H * H / 4);
  const float4* c4 = reinterpret_cast<const float4*>(&cs[nl][0]);
  for (int i = 0; i < H; ++i) {
    float part = 0.f;
    #pragma unroll 4
    for (int j4 = 0; j4 < H / 4; ++j4) {
      const float4 wv = W4[i * (H / 4) + j4];
      const float4 cv = c4[j4];
      part += wv.x * cv.x + wv.y * cv.y + wv.z * cv.z + wv.w * cv.w;
    }
    acc += qs[nl][i] * part;
  }
  xout[n * H + o] = fmaxf(acc, 0.f);
}

// ---------------- adjacency compaction ----------------
__global__ __launch_bounds__(256) void k_compact(
    const float* __restrict__ adj, int* __restrict__ nbr, int* __restrict__ deg)
{
  const int w = threadIdx.x >> 6, lane = threadIdx.x & 63;
  const int i = blockIdx.x * 4 + w;
  int base = 0;
  for (int j0 = 0; j0 < N; j0 += 64) {
    const float v = adj[(long)i * N + j0 + lane];
    const unsigned long long mask = __ballot(v > 0.f);
    const int pre = __popcll(mask & ((1ull << lane) - 1ull));
    if (v > 0.f && base + pre < CAP) nbr[i * CAP + base + pre] = j0 + lane;
    base += __popcll(mask);
  }
  if (lane == 0) deg[i] = base < CAP ? base : CAP;
}

// ---------------- GAT precompute Wh, s1, s2 ----------------
__global__ __launch_bounds__(256) void k_gat_pre(
    const float* __restrict__ x, const float* __restrict__ W,
    const float* __restrict__ a, const int F,
    float* __restrict__ Wh, float* __restrict__ s1, float* __restrict__ s2)
{
  const int nl = threadIdx.x >> 6, o = threadIdx.x & 63;
  const int n = blockIdx.x * 4 + nl;
  const int u = blockIdx.y;
  const float* __restrict__ Wu = W + (long)u * F * 64;
  const float* __restrict__ xn = x + (long)n * F;
  float acc = 0.f;
  #pragma unroll 8
  for (int f = 0; f < F; ++f) acc += xn[f] * Wu[f * 64 + o];
  Wh[((long)u * N + n) * 64 + o] = acc;
  float p1 = acc * a[u * 128 + o];
  float p2 = acc * a[u * 128 + 64 + o];
  #pragma unroll
  for (int d = 32; d > 0; d >>= 1) { p1 += __shfl_xor(p1, d, 64); p2 += __shfl_xor(p2, d, 64); }
  if (o == 0) { s1[u * N + n] = p1; s2[u * N + n] = p2; }
}

// ---------------- GAT attention (sparse, compacted) ----------------
__global__ __launch_bounds__(256) void k_gat_attn(
    const float* __restrict__ Wh, const float* __restrict__ s1,
    const float* __restrict__ s2, const int* __restrict__ nbr,
    const int* __restrict__ deg, const int mode, float* __restrict__ out)
{
  __shared__ float ew[4][CAP];
  __shared__ int nb[4][CAP];
  const int w = threadIdx.x >> 6, lane = threadIdx.x & 63;
  const int row = blockIdx.x * 4 + w;
  const int u = row >> 11;          // / N
  const int i = row & (N - 1);
  const int d = deg[i];
  const float su = s1[u * N + i];
  float mx = -1e30f;
  for (int t = lane; t < d; t += 64) {
    const int j = nbr[i * CAP + t];
    float e = su + s2[u * N + j];
    e = e > 0.f ? e : SLOPE * e;
    ew[w][t] = e; nb[w][t] = j;
    mx = fmaxf(mx, e);
  }
  #pragma unroll
  for (int dd = 32; dd > 0; dd >>= 1) mx = fmaxf(mx, __shfl_xor(mx, dd, 64));
  float sm = 0.f;
  for (int t = lane; t < d; t += 64) {
    const float ex = expf(ew[w][t] - mx);
    ew[w][t] = ex;
    sm += ex;
  }
  #pragma unroll
  for (int dd = 32; dd > 0; dd >>= 1) sm += __shfl_xor(sm, dd, 64);
  __syncthreads();
  const float inv = 1.f / sm;
  float acc = 0.f;
  for (int t = 0; t < d; ++t) {
    const float att = ew[w][t];
    const int j = nb[w][t];
    acc += att * Wh[((long)u * N + j) * 64 + lane];
  }
  acc *= inv;
  float val;
  if (mode == 0) val = acc > 0.f ? acc : (expf(acc) - 1.f);   // elu, alpha=1
  else           val = 1.f / (1.f + expf(-acc));              // sigmoid
  out[(long)i * (U * 64) + u * 64 + lane] = val;
}

// ---------------- final projection + sigmoid ----------------
__global__ __launch_bounds__(256) void k_final(
    const float* __restrict__ nz, const float* __restrict__ fw,
    const float* __restrict__ fb, float* __restrict__ out)
{
  const int w = threadIdx.x >> 6, lane = threadIdx.x & 63;
  const int n = blockIdx.x * 4 + w;
  float p = 0.f;
  #pragma unroll
  for (int f = lane; f < 512; f += 64) p += nz[(long)n * 512 + f] * fw[f];
  #pragma unroll
  for (int d = 32; d > 0; d >>= 1) p += __shfl_xor(p, d, 64);
  if (lane == 0) out[n] = 1.f / (1.f + expf(-(p + fb[0])));
}

}  // namespace

extern "C" void kernel_launch(void* const* d_in, const int* in_sizes, int n_in,
                              void* d_out, int out_size, void* d_ws, size_t ws_size,
                              hipStream_t stream)
{
  const float* p     = (const float*)d_in[0];
  const float* m     = (const float*)d_in[1];
  const float* adj   = (const float*)d_in[2];
  const float* Wih_p = (const float*)d_in[3];
  const float* Whh_p = (const float*)d_in[4];
  const float* bih_p = (const float*)d_in[5];
  const float* bhh_p = (const float*)d_in[6];
  const float* Wih_m = (const float*)d_in[7];
  const float* Whh_m = (const float*)d_in[8];
  const float* bih_m = (const float*)d_in[9];
  const float* bhh_m = (const float*)d_in[10];
  const float* Wih_s = (const float*)d_in[11];
  const float* Whh_s = (const float*)d_in[12];
  const float* bih_s = (const float*)d_in[13];
  const float* bhh_s = (const float*)d_in[14];
  // d_in[15..23]: lin-attn weights — unused (softmax over size-1 axis == 1)
  const float* blend_W = (const float*)d_in[24];
  const float* blend_b = (const float*)d_in[25];
  const float* g1W = (const float*)d_in[26];
  const float* g1a = (const float*)d_in[27];
  const float* g2W = (const float*)d_in[28];
  const float* g2a = (const float*)d_in[29];
  const float* finW = (const float*)d_in[30];
  const float* finb = (const float*)d_in[31];

  float* ws = (float*)d_ws;
  float* q    = ws;                  // N*H
  float* rr   = q + N * H;           // N*T*H
  float* c    = rr + N * T * H;      // N*H
  float* xb   = c + N * H;           // N*H
  float* Wh1  = xb + N * H;          // U*N*64
  float* s1a  = Wh1 + U * N * 64;    // U*N
  float* s2a  = s1a + U * N;         // U*N
  float* z    = s2a + U * N;         // N*512
  float* Wh2  = z + (long)N * 512;   // U*N*64
  float* s1b  = Wh2 + U * N * 64;    // U*N
  float* s2b  = s1b + U * N;         // U*N
  float* nz   = s2b + U * N;         // N*512
  int*   nbr  = (int*)(nz + (long)N * 512);   // N*CAP ints
  int*   deg  = nbr + (long)N * CAP;          // N ints
  short* WihH = (short*)(deg + N);            // 192*E bf16
  short* WihL = WihH + 192 * E;               // 192*E bf16
  float* WhhT = (float*)(WihL + 192 * E);     // 64*192 fp32
  float* gi   = WhhT + 64 * 192;              // chunked: up to 10240*K*192 fp32

  // chunk the gi buffer to whatever scratch remains (deterministic in ws_size)
  const long avail = (long)(ws_size / 4) - (gi - ws);
  const long total_seqs = (long)T * N;                       // 10240
  long chunk = (avail / ((long)K * 192) / 16) * 16;
  if (chunk > total_seqs) chunk = total_seqs;
  if (chunk < 16) chunk = 16;

  k_prep<<<64, 256, 0, stream>>>(Wih_m, Whh_m, WihH, WihL, WhhT);
  k_gru_p<<<N / 4, 256, 0, stream>>>(p, Wih_p, Whh_p, bih_p, bhh_p, q);
  for (long s0 = 0; s0 < total_seqs; s0 += chunk) {
    const int cs = (int)((total_seqs - s0) < chunk ? (total_seqs - s0) : chunk);
    k_gemm<<<cs * K / 64, 256, 0, stream>>>(m, WihH, WihL, bih_m, gi, (int)(s0 * K));
    k_recur<<<cs / 16, 256, 0, stream>>>(gi, WhhT, bhh_m, rr, (int)s0);
  }
  k_gru_s<<<N / 4, 256, 0, stream>>>(rr, Wih_s, Whh_s, bih_s, bhh_s, c);
  k_blend<<<N / 4, 256, 0, stream>>>(q, c, blend_W, blend_b, xb);
  k_compact<<<N / 4, 256, 0, stream>>>(adj, nbr, deg);
  k_gat_pre<<<dim3(N / 4, U), 256, 0, stream>>>(xb, g1W, g1a, 64, Wh1, s1a, s2a);
  k_gat_attn<<<(U * N) / 4, 256, 0, stream>>>(Wh1, s1a, s2a, nbr, deg, 0, z);
  k_gat_pre<<<dim3(N / 4, U), 256, 0, stream>>>(z, g2W, g2a, 512, Wh2, s1b, s2b);
  k_gat_attn<<<(U * N) / 4, 256, 0, stream>>>(Wh2, s1b, s2b, nbr, deg, 1, nz);
  k_final<<<N / 4, 256, 0, stream>>>(nz, finW, finb, (float*)d_out);
}

// Round 3
// 1016.147 us; speedup vs baseline: 5.0508x; 1.3898x over previous
//
#include <hip/hip_runtime.h>
#include <math.h>

namespace {

constexpr int T = 5, N = 2048, K = 20, E = 512;
constexpr int H = 64, U = 8;
constexpr int CAP = 512;           // max neighbors kept (measured mean ~103)
constexpr float SLOPE = 0.01f;

typedef __attribute__((ext_vector_type(8))) short short8;
typedef __attribute__((ext_vector_type(4))) float f32x4;

__device__ inline float sigm(float x) { return 1.0f / (1.0f + expf(-x)); }

// split fp32 -> bf16 hi + bf16 lo (truncation; x ~= hi+lo with rel err <= 2^-16)
__device__ inline void bsplit(float x, short& hi, short& lo) {
  unsigned u = __float_as_uint(x);
  hi = (short)(u >> 16);
  float r = x - __uint_as_float(u & 0xFFFF0000u);
  lo = (short)(__float_as_uint(r) >> 16);
}

// ---------------- prep: Wih_m -> blocked bf16 cell layout, Whh_m -> transposed ----
// Bcells layout: [bk(8)][hl(2)][oct(8)][nt(12)][lr(16)][j(8)]  (shorts)
// cell content = split(Wih[nt*16+lr][bk*64 + oct*8 + j])
__global__ __launch_bounds__(256) void k_prep(
    const float* __restrict__ Wih, const float* __restrict__ Whh,
    short* __restrict__ Bcells, float* __restrict__ WhhT)
{
  for (int idx = threadIdx.x + blockIdx.x * 256; idx < 192 * E; idx += 256 * 64) {
    const int col = idx >> 9, k = idx & 511;
    short hi, lo; bsplit(Wih[idx], hi, lo);
    const int bk = k >> 6, oct = (k >> 3) & 7, j = k & 7;
    const int nt = col >> 4, lr = col & 15;
    const long base = ((long)bk * 2 * 96 + oct * 12 + nt) * 128 + lr * 8 + j;
    Bcells[base] = hi;                    // hl=0
    Bcells[base + 96 * 128] = lo;         // hl=1
  }
  for (int idx = threadIdx.x + blockIdx.x * 256; idx < 64 * 192; idx += 256 * 64) {
    const int k2 = idx / 192, row = idx % 192;
    WhhT[idx] = Whh[row * 64 + k2];
  }
}

// ---------------- gi GEMM: [rows,512] x [512,192], bf16 MFMA split-precision ------
// block: 256 thr / 4 waves; tile M=128 x N=192, BK=64.
// A staged via regs (fp32 -> bsplit -> LDS cells); B staged via global_load_lds.
__global__ __launch_bounds__(256) void k_gemm(
    const float* __restrict__ m, const short* __restrict__ Bcells,
    const float* __restrict__ bih, float* __restrict__ gi, const long row0)
{
  // A cells: [hl(2)][oct(8)][rowgrp(8)][lr(16)][j(8)] ; B cells: [hl][oct][nt(12)][lr][j]
  __shared__ alignas(16) short Ac[2 * 8 * 8 * 16 * 8];    // 32 KB
  __shared__ alignas(16) short Bc[2 * 8 * 12 * 16 * 8];   // 48 KB
  const int tid = threadIdx.x;
  const int w = tid >> 6, l = tid & 63;
  const int lr = l & 15, g = l >> 4;
  const long blkrow = (long)blockIdx.x * 128;

  f32x4 acc[2][12];
  #pragma unroll
  for (int mf = 0; mf < 2; ++mf)
    #pragma unroll
    for (int nt = 0; nt < 12; ++nt) acc[mf][nt] = (f32x4){0.f, 0.f, 0.f, 0.f};

  const int arow_l = tid >> 3;        // 0..31 (+ i*32)
  const int aoct = tid & 7;

  for (int bk = 0; bk < 8; ++bk) {
    // ---- B: async global->LDS, 48 chunks of 1KB, linear ----
    {
      const short* __restrict__ bsrc = Bcells + (long)bk * 24576;
      #pragma unroll
      for (int i = 0; i < 12; ++i) {
        const int c = w + i * 4;
        __builtin_amdgcn_global_load_lds(
            (const __attribute__((address_space(1))) void*)(bsrc + c * 512 + l * 8),
            (__attribute__((address_space(3))) void*)(&Bc[c * 512]), 16, 0, 0);
      }
    }
    // ---- A: global (coalesced 256B/8-lane segments) -> bsplit -> LDS cells ----
    #pragma unroll
    for (int i = 0; i < 4; ++i) {
      const int rl = arow_l + i * 32;
      const float* __restrict__ src = m + (row0 + blkrow + rl) * E + bk * 64 + aoct * 8;
      const float4 v0 = *reinterpret_cast<const float4*>(src);
      const float4 v1 = *reinterpret_cast<const float4*>(src + 4);
      short h0,l0,h1,l1,h2,l2,h3,l3,h4,l4,h5,l5,h6,l6,h7,l7;
      bsplit(v0.x,h0,l0); bsplit(v0.y,h1,l1); bsplit(v0.z,h2,l2); bsplit(v0.w,h3,l3);
      bsplit(v1.x,h4,l4); bsplit(v1.y,h5,l5); bsplit(v1.z,h6,l6); bsplit(v1.w,h7,l7);
      const int cell = (aoct * 8 + (rl >> 4)) * 16 + (rl & 15);
      *reinterpret_cast<short8*>(&Ac[cell * 8]) = (short8){h0,h1,h2,h3,h4,h5,h6,h7};
      *reinterpret_cast<short8*>(&Ac[8192 + cell * 8]) = (short8){l0,l1,l2,l3,l4,l5,l6,l7};
    }
    __syncthreads();

    // ---- compute: 2 kc x 12 nt x 2 mf x 3 passes ----
    #pragma unroll
    for (int kc = 0; kc < 2; ++kc) {
      const int oct = kc * 4 + g;
      short8 ah[2], al[2];
      #pragma unroll
      for (int mf = 0; mf < 2; ++mf) {
        const int cell = (oct * 8 + (w * 2 + mf)) * 16 + lr;
        ah[mf] = *reinterpret_cast<const short8*>(&Ac[cell * 8]);
        al[mf] = *reinterpret_cast<const short8*>(&Ac[8192 + cell * 8]);
      }
      #pragma unroll
      for (int nt = 0; nt < 12; ++nt) {
        const int bcell = (oct * 12 + nt) * 16 + lr;
        const short8 bh = *reinterpret_cast<const short8*>(&Bc[bcell * 8]);
        const short8 bl = *reinterpret_cast<const short8*>(&Bc[12288 + bcell * 8]);
        #pragma unroll
        for (int mf = 0; mf < 2; ++mf) {
          acc[mf][nt] = __builtin_amdgcn_mfma_f32_16x16x32_bf16(ah[mf], bh, acc[mf][nt], 0, 0, 0);
          acc[mf][nt] = __builtin_amdgcn_mfma_f32_16x16x32_bf16(al[mf], bh, acc[mf][nt], 0, 0, 0);
          acc[mf][nt] = __builtin_amdgcn_mfma_f32_16x16x32_bf16(ah[mf], bl, acc[mf][nt], 0, 0, 0);
        }
      }
    }
    __syncthreads();
  }

  // epilogue: C/D layout col = lane&15, row = (lane>>4)*4 + reg
  #pragma unroll
  for (int mf = 0; mf < 2; ++mf) {
    const long rbase = blkrow + w * 32 + mf * 16 + g * 4;
    #pragma unroll
    for (int nt = 0; nt < 12; ++nt) {
      const int col = nt * 16 + lr;
      const float bb = bih[col];
      #pragma unroll
      for (int i = 0; i < 4; ++i)
        gi[(rbase + i) * 192 + col] = acc[mf][nt][i] + bb;
    }
  }
}

// ---------------- recurrence over K=20 using precomputed gi ----------------
__global__ __launch_bounds__(256) void k_recur(
    const float* __restrict__ gi, const float* __restrict__ WhhT,
    const float* __restrict__ bhh, float* __restrict__ rout, const int seq0)
{
  __shared__ float wsh[64][192];   // 48 KB
  __shared__ float hs[16][64];     // 4 KB
  const int tid = threadIdx.x;
  for (int idx = tid; idx < 64 * 192; idx += 256) wsh[idx / 192][idx % 192] = WhhT[idx];
  for (int idx = tid; idx < 16 * 64; idx += 256) hs[idx >> 6][idx & 63] = 0.f;
  __syncthreads();

  const int w = tid >> 6, l = tid & 63;
  const int sl0 = w * 4;
  const int lseq0 = blockIdx.x * 16 + sl0;
  const float bR = bhh[l], bZ = bhh[64 + l], bN = bhh[128 + l];
  float rsum[4] = {0.f, 0.f, 0.f, 0.f};

  for (int k = 0; k < K; ++k) {
    float aR[4], aZ[4], aN[4], gR[4], gZ[4], gN[4];
    #pragma unroll
    for (int ii = 0; ii < 4; ++ii) {
      const long row = ((long)(lseq0 + ii) * K + k) * 192;
      gR[ii] = gi[row + l]; gZ[ii] = gi[row + 64 + l]; gN[ii] = gi[row + 128 + l];
      aR[ii] = bR; aZ[ii] = bZ; aN[ii] = bN;
    }
    #pragma unroll 4
    for (int k2 = 0; k2 < H; ++k2) {
      const float wr = wsh[k2][l], wz = wsh[k2][64 + l], wn = wsh[k2][128 + l];
      #pragma unroll
      for (int ii = 0; ii < 4; ++ii) {
        const float hk = hs[sl0 + ii][k2];
        aR[ii] += wr * hk; aZ[ii] += wz * hk; aN[ii] += wn * hk;
      }
    }
    #pragma unroll
    for (int ii = 0; ii < 4; ++ii) {
      const float r = sigm(gR[ii] + aR[ii]);
      const float z = sigm(gZ[ii] + aZ[ii]);
      const float nn = tanhf(gN[ii] + r * aN[ii]);
      const float h = (1.f - z) * nn + z * hs[sl0 + ii][l];
      rsum[ii] += h;
      hs[sl0 + ii][l] = h;
    }
  }
  #pragma unroll
  for (int ii = 0; ii < 4; ++ii) {
    const int gseq = seq0 + lseq0 + ii;
    const int tt = gseq / N, n = gseq % N;
    rout[(n * T + tt) * H + l] = rsum[ii];
  }
}

// ---------------- GRU over p, q = sum_t h ----------------
__global__ __launch_bounds__(256) void k_gru_p(
    const float* __restrict__ p, const float* __restrict__ Wih,
    const float* __restrict__ Whh, const float* __restrict__ bih,
    const float* __restrict__ bhh, float* __restrict__ q)
{
  __shared__ float hs[4][H];
  const int w = threadIdx.x >> 6, lane = threadIdx.x & 63;
  const int n = blockIdx.x * 4 + w;
  hs[w][lane] = 0.f;
  float h = 0.f, qs = 0.f;
  __syncthreads();
  for (int t = 0; t < T; ++t) {
    const float x0 = p[n * (T * 3) + t * 3 + 0];
    const float x1 = p[n * (T * 3) + t * 3 + 1];
    const float x2 = p[n * (T * 3) + t * 3 + 2];
    float gr = bih[lane]     + Wih[lane * 3] * x0       + Wih[lane * 3 + 1] * x1       + Wih[lane * 3 + 2] * x2;
    float gz = bih[64 + lane]  + Wih[(64 + lane) * 3] * x0  + Wih[(64 + lane) * 3 + 1] * x1  + Wih[(64 + lane) * 3 + 2] * x2;
    float gn = bih[128 + lane] + Wih[(128 + lane) * 3] * x0 + Wih[(128 + lane) * 3 + 1] * x1 + Wih[(128 + lane) * 3 + 2] * x2;
    float hr = bhh[lane], hz = bhh[64 + lane], hn = bhh[128 + lane];
    #pragma unroll 8
    for (int k2 = 0; k2 < H; ++k2) {
      const float hk = hs[w][k2];
      hr += Whh[lane * H + k2] * hk;
      hz += Whh[(64 + lane) * H + k2] * hk;
      hn += Whh[(128 + lane) * H + k2] * hk;
    }
    const float r = sigm(gr + hr), z = sigm(gz + hz);
    const float nn = tanhf(gn + r * hn);
    h = (1.f - z) * nn + z * h;
    qs += h;
    __syncthreads();
    hs[w][lane] = h;
    __syncthreads();
  }
  q[n * H + lane] = qs;
}

// ---------------- GRU over r, c = sum_t h ----------------
__global__ __launch_bounds__(256) void k_gru_s(
    const float* __restrict__ rin, const float* __restrict__ Wih,
    const float* __restrict__ Whh, const float* __restrict__ bih,
    const float* __restrict__ bhh, float* __restrict__ c)
{
  __shared__ float hs[4][H];
  __shared__ float xsh[4][H];
  const int w = threadIdx.x >> 6, lane = threadIdx.x & 63;
  const int n = blockIdx.x * 4 + w;
  hs[w][lane] = 0.f;
  float h = 0.f, cs = 0.f;
  __syncthreads();
  for (int t = 0; t < T; ++t) {
    xsh[w][lane] = rin[(n * T + t) * H + lane];
    __syncthreads();
    float gr = bih[lane], gz = bih[64 + lane], gn = bih[128 + lane];
    float hr = bhh[lane], hz = bhh[64 + lane], hn = bhh[128 + lane];
    #pragma unroll 8
    for (int k2 = 0; k2 < H; ++k2) {
      const float xk = xsh[w][k2];
      const float hk = hs[w][k2];
      gr += Wih[lane * H + k2] * xk;  gz += Wih[(64 + lane) * H + k2] * xk;  gn += Wih[(128 + lane) * H + k2] * xk;
      hr += Whh[lane * H + k2] * hk;  hz += Whh[(64 + lane) * H + k2] * hk;  hn += Whh[(128 + lane) * H + k2] * hk;
    }
    const float r = sigm(gr + hr), z = sigm(gz + hz);
    const float nn = tanhf(gn + r * hn);
    h = (1.f - z) * nn + z * h;
    cs += h;
    __syncthreads();
    hs[w][lane] = h;
    __syncthreads();
  }
  c[n * H + lane] = cs;
}

// ---------------- bilinear blend + relu ----------------
__global__ __launch_bounds__(256) void k_blend(
    const float* __restrict__ q, const float* __restrict__ c,
    const float* __restrict__ W, const float* __restrict__ b,
    float* __restrict__ xout)
{
  __shared__ alignas(16) float qs[4][H];
  __shared__ alignas(16) float cs[4][H];
  const int nl = threadIdx.x >> 6, o = threadIdx.x & 63;
  const int n = blockIdx.x * 4 + nl;
  qs[nl][o] = q[n * H + o];
  cs[nl][o] = c[n * H + o];
  __syncthreads();
  float acc = b[o];
  const float4* __restrict__ W4 = reinterpret_cast<const float4*>(W) + o * (H * H / 4);
  const float4* c4 = reinterpret_cast<const float4*>(&cs[nl][0]);
  for (int i = 0; i < H; ++i) {
    float part = 0.f;
    #pragma unroll 4
    for (int j4 = 0; j4 < H / 4; ++j4) {
      const float4 wv = W4[i * (H / 4) + j4];
      const float4 cv = c4[j4];
      part += wv.x * cv.x + wv.y * cv.y + wv.z * cv.z + wv.w * cv.w;
    }
    acc += qs[nl][i] * part;
  }
  xout[n * H + o] = fmaxf(acc, 0.f);
}

// ---------------- adjacency compaction ----------------
__global__ __launch_bounds__(256) void k_compact(
    const float* __restrict__ adj, int* __restrict__ nbr, int* __restrict__ deg)
{
  const int w = threadIdx.x >> 6, lane = threadIdx.x & 63;
  const int i = blockIdx.x * 4 + w;
  int base = 0;
  for (int j0 = 0; j0 < N; j0 += 64) {
    const float v = adj[(long)i * N + j0 + lane];
    const unsigned long long mask = __ballot(v > 0.f);
    const int pre = __popcll(mask & ((1ull << lane) - 1ull));
    if (v > 0.f && base + pre < CAP) nbr[i * CAP + base + pre] = j0 + lane;
    base += __popcll(mask);
  }
  if (lane == 0) deg[i] = base < CAP ? base : CAP;
}

// ---------------- GAT precompute Wh, s1, s2 ----------------
__global__ __launch_bounds__(256) void k_gat_pre(
    const float* __restrict__ x, const float* __restrict__ W,
    const float* __restrict__ a, const int F,
    float* __restrict__ Wh, float* __restrict__ s1, float* __restrict__ s2)
{
  const int nl = threadIdx.x >> 6, o = threadIdx.x & 63;
  const int n = blockIdx.x * 4 + nl;
  const int u = blockIdx.y;
  const float* __restrict__ Wu = W + (long)u * F * 64;
  const float* __restrict__ xn = x + (long)n * F;
  float acc = 0.f;
  #pragma unroll 8
  for (int f = 0; f < F; ++f) acc += xn[f] * Wu[f * 64 + o];
  Wh[((long)u * N + n) * 64 + o] = acc;
  float p1 = acc * a[u * 128 + o];
  float p2 = acc * a[u * 128 + 64 + o];
  #pragma unroll
  for (int d = 32; d > 0; d >>= 1) { p1 += __shfl_xor(p1, d, 64); p2 += __shfl_xor(p2, d, 64); }
  if (o == 0) { s1[u * N + n] = p1; s2[u * N + n] = p2; }
}

// ---------------- GAT attention (sparse, compacted) ----------------
__global__ __launch_bounds__(256) void k_gat_attn(
    const float* __restrict__ Wh, const float* __restrict__ s1,
    const float* __restrict__ s2, const int* __restrict__ nbr,
    const int* __restrict__ deg, const int mode, float* __restrict__ out)
{
  __shared__ float ew[4][CAP];
  __shared__ int nb[4][CAP];
  const int w = threadIdx.x >> 6, lane = threadIdx.x & 63;
  const int row = blockIdx.x * 4 + w;
  const int u = row >> 11;
  const int i = row & (N - 1);
  const int d = deg[i];
  const float su = s1[u * N + i];
  float mx = -1e30f;
  for (int t = lane; t < d; t += 64) {
    const int j = nbr[i * CAP + t];
    float e = su + s2[u * N + j];
    e = e > 0.f ? e : SLOPE * e;
    ew[w][t] = e; nb[w][t] = j;
    mx = fmaxf(mx, e);
  }
  #pragma unroll
  for (int dd = 32; dd > 0; dd >>= 1) mx = fmaxf(mx, __shfl_xor(mx, dd, 64));
  float sm = 0.f;
  for (int t = lane; t < d; t += 64) {
    const float ex = expf(ew[w][t] - mx);
    ew[w][t] = ex;
    sm += ex;
  }
  #pragma unroll
  for (int dd = 32; dd > 0; dd >>= 1) sm += __shfl_xor(sm, dd, 64);
  __syncthreads();
  const float inv = 1.f / sm;
  float acc = 0.f;
  for (int t = 0; t < d; ++t) {
    const float att = ew[w][t];
    const int j = nb[w][t];
    acc += att * Wh[((long)u * N + j) * 64 + lane];
  }
  acc *= inv;
  float val;
  if (mode == 0) val = acc > 0.f ? acc : (expf(acc) - 1.f);
  else           val = 1.f / (1.f + expf(-acc));
  out[(long)i * (U * 64) + u * 64 + lane] = val;
}

// ---------------- final projection + sigmoid ----------------
__global__ __launch_bounds__(256) void k_final(
    const float* __restrict__ nz, const float* __restrict__ fw,
    const float* __restrict__ fb, float* __restrict__ out)
{
  const int w = threadIdx.x >> 6, lane = threadIdx.x & 63;
  const int n = blockIdx.x * 4 + w;
  float p = 0.f;
  #pragma unroll
  for (int f = lane; f < 512; f += 64) p += nz[(long)n * 512 + f] * fw[f];
  #pragma unroll
  for (int d = 32; d > 0; d >>= 1) p += __shfl_xor(p, d, 64);
  if (lane == 0) out[n] = 1.f / (1.f + expf(-(p + fb[0])));
}

}  // namespace

extern "C" void kernel_launch(void* const* d_in, const int* in_sizes, int n_in,
                              void* d_out, int out_size, void* d_ws, size_t ws_size,
                              hipStream_t stream)
{
  const float* p     = (const float*)d_in[0];
  const float* m     = (const float*)d_in[1];
  const float* adj   = (const float*)d_in[2];
  const float* Wih_p = (const float*)d_in[3];
  const float* Whh_p = (const float*)d_in[4];
  const float* bih_p = (const float*)d_in[5];
  const float* bhh_p = (const float*)d_in[6];
  const float* Wih_m = (const float*)d_in[7];
  const float* Whh_m = (const float*)d_in[8];
  const float* bih_m = (const float*)d_in[9];
  const float* bhh_m = (const float*)d_in[10];
  const float* Wih_s = (const float*)d_in[11];
  const float* Whh_s = (const float*)d_in[12];
  const float* bih_s = (const float*)d_in[13];
  const float* bhh_s = (const float*)d_in[14];
  // d_in[15..23]: lin-attn weights — unused (softmax over size-1 axis == 1)
  const float* blend_W = (const float*)d_in[24];
  const float* blend_b = (const float*)d_in[25];
  const float* g1W = (const float*)d_in[26];
  const float* g1a = (const float*)d_in[27];
  const float* g2W = (const float*)d_in[28];
  const float* g2a = (const float*)d_in[29];
  const float* finW = (const float*)d_in[30];
  const float* finb = (const float*)d_in[31];

  float* ws = (float*)d_ws;
  float* q    = ws;                  // N*H
  float* rr   = q + N * H;           // N*T*H
  float* c    = rr + N * T * H;      // N*H
  float* xb   = c + N * H;           // N*H
  float* Wh1  = xb + N * H;          // U*N*64
  float* s1a  = Wh1 + U * N * 64;    // U*N
  float* s2a  = s1a + U * N;         // U*N
  float* z    = s2a + U * N;         // N*512
  float* Wh2  = z + (long)N * 512;   // U*N*64
  float* s1b  = Wh2 + U * N * 64;    // U*N
  float* s2b  = s1b + U * N;         // U*N
  float* nz   = s2b + U * N;         // N*512
  int*   nbr  = (int*)(nz + (long)N * 512);   // N*CAP ints
  int*   deg  = nbr + (long)N * CAP;          // N ints
  short* Bcells = (short*)(deg + N);          // 2*192*512 shorts (hi+lo blocked)
  float* WhhT = (float*)(Bcells + 2 * 192 * E);  // 64*192 fp32
  float* gi   = WhhT + 64 * 192;              // chunked

  // chunk the gi buffer to whatever scratch remains (deterministic in ws_size)
  const long avail = (long)(ws_size / 4) - (gi - ws);
  const long total_seqs = (long)T * N;                       // 10240
  long chunk = (avail / ((long)K * 192) / 32) * 32;          // mult of 32 seqs (640 rows)
  if (chunk > total_seqs) chunk = total_seqs;
  if (chunk < 32) chunk = 32;

  k_prep<<<64, 256, 0, stream>>>(Wih_m, Whh_m, Bcells, WhhT);
  k_gru_p<<<N / 4, 256, 0, stream>>>(p, Wih_p, Whh_p, bih_p, bhh_p, q);
  for (long s0 = 0; s0 < total_seqs; s0 += chunk) {
    const long cs = (total_seqs - s0) < chunk ? (total_seqs - s0) : chunk;
    k_gemm<<<(int)(cs * K / 128), 256, 0, stream>>>(m, Bcells, bih_m, gi, s0 * K);
    k_recur<<<(int)(cs / 16), 256, 0, stream>>>(gi, WhhT, bhh_m, rr, (int)s0);
  }
  k_gru_s<<<N / 4, 256, 0, stream>>>(rr, Wih_s, Whh_s, bih_s, bhh_s, c);
  k_blend<<<N / 4, 256, 0, stream>>>(q, c, blend_W, blend_b, xb);
  k_compact<<<N / 4, 256, 0, stream>>>(adj, nbr, deg);
  k_gat_pre<<<dim3(N / 4, U), 256, 0, stream>>>(xb, g1W, g1a, 64, Wh1, s1a, s2a);
  k_gat_attn<<<(U * N) / 4, 256, 0, stream>>>(Wh1, s1a, s2a, nbr, deg, 0, z);
  k_gat_pre<<<dim3(N / 4, U), 256, 0, stream>>>(z, g2W, g2a, 512, Wh2, s1b, s2b);
  k_gat_attn<<<(U * N) / 4, 256, 0, stream>>>(Wh2, s1b, s2b, nbr, deg, 1, nz);
  k_final<<<N / 4, 256, 0, stream>>>(nz, finW, finb, (float*)d_out);
}